// Round 5
// baseline (54.499 us; speedup 1.0000x reference)
//
#include <hip/hip_runtime.h>
#include <math.h>

#define NB 4
#define NN 512
#define ND 128
#define NC 10
#define TILE 32
#define PAD 132        // Xj row stride: stride-16 rows differ by 4 banks -> worst 2-way (free)
#define CHUNKS (ND/4)  // 32

typedef float f32x2 __attribute__((ext_vector_type(2)));

// one 4-wide d-chunk of the bilinear accumulation (all indices compile-time after inline)
static __device__ __forceinline__ void mac_chunk(
    const float4 (&af)[2], const float4 (&bf)[2], const float (&w)[40],
    float (&acc)[2][2][NC])
{
    float prd[2][2][4];
    #pragma unroll
    for (int p = 0; p < 2; ++p)
        #pragma unroll
        for (int q = 0; q < 2; ++q) {
            prd[p][q][0] = af[p].x * bf[q].x;
            prd[p][q][1] = af[p].y * bf[q].y;
            prd[p][q][2] = af[p].z * bf[q].z;
            prd[p][q][3] = af[p].w * bf[q].w;
        }
    #pragma unroll
    for (int dd = 0; dd < 4; ++dd)
        #pragma unroll
        for (int c = 0; c < NC; ++c)
            #pragma unroll
            for (int p = 0; p < 2; ++p)
                #pragma unroll
                for (int q = 0; q < 2; ++q)
                    acc[p][q][c] = fmaf(prd[p][q][dd], w[dd * NC + c], acc[p][q][c]);
}

__global__ __launch_bounds__(256) void w2ner_main(
    const float* __restrict__ x, const int* __restrict__ span,
    const int* __restrict__ seqlen, const float* __restrict__ Wm,
    const float* __restrict__ bias, float* __restrict__ out,
    float* __restrict__ accum)
{
    __shared__ float sXj[TILE * PAD];
    __shared__ float sRed[4 * 5];

    const int tid = threadIdx.x;
    const int ntj = NN / TILE;                  // 16
    const int blk = blockIdx.x;
    const int b   = blk / (ntj * ntj);
    const int rem = blk % (ntj * ntj);
    const int i0  = (rem / ntj) * TILE;
    const int j0  = (rem % ntj) * TILE;

    const float* xb = x + (size_t)b * NN * ND;

    // stage Xj tile only (coalesced float4)
    for (int idx = tid; idx < TILE * (ND / 4); idx += 256) {
        int row = idx >> 5;            // 32 float4 per row
        int c4  = (idx & 31) << 2;
        float4 vj = *reinterpret_cast<const float4*>(xb + (size_t)(j0 + row) * ND + c4);
        *reinterpret_cast<float4*>(sXj + row * PAD + c4) = vj;
    }

    const int ti = tid >> 4;   // 0..15 -> rows ti, ti+16
    const int tj = tid & 15;   // 0..15 -> cols tj, tj+16

    // prefetch span for the 4 pairs this thread owns (hides under K-loop)
    size_t offs[2][2];
    int sp[2][2];
    #pragma unroll
    for (int p = 0; p < 2; ++p)
        #pragma unroll
        for (int q = 0; q < 2; ++q) {
            const int i = i0 + ti + p * 16;
            const int j = j0 + tj + q * 16;
            offs[p][q] = (size_t)b * NN * NN + (size_t)i * NN + j;
            sp[p][q]   = span[offs[p][q]];
        }
    const int sl = seqlen[b];

    __syncthreads();

    float acc[2][2][NC];
    #pragma unroll
    for (int p = 0; p < 2; ++p)
        #pragma unroll
        for (int q = 0; q < 2; ++q)
            #pragma unroll
            for (int c = 0; c < NC; ++c) acc[p][q][c] = 0.f;

    // Xi read straight from global: 16 lanes share the address -> broadcast, vmcnt path
    const float* gXi0 = xb + (size_t)(i0 + ti) * ND;
    const float* gXi1 = xb + (size_t)(i0 + ti + 16) * ND;
    const float* pXj0 = sXj + tj * PAD;
    const float* pXj1 = sXj + (tj + 16) * PAD;

#define LOADW(buf, t) do { const float* _wp = Wm + (t) * 40; \
    _Pragma("unroll") for (int _k = 0; _k < 40; ++_k) (buf)[_k] = _wp[_k]; } while (0)
#define LOADX(xi, xj, t) do { \
    (xi)[0] = *reinterpret_cast<const float4*>(gXi0 + 4 * (t)); \
    (xi)[1] = *reinterpret_cast<const float4*>(gXi1 + 4 * (t)); \
    (xj)[0] = *reinterpret_cast<const float4*>(pXj0 + 4 * (t)); \
    (xj)[1] = *reinterpret_cast<const float4*>(pXj1 + 4 * (t)); } while (0)

    float  wA[40], wB[40];
    float4 xiA[2], xjA[2], xiB[2], xjB[2];

    LOADW(wA, 0);
    LOADX(xiA, xjA, 0);

    for (int t = 0; t < CHUNKS; t += 2) {
        LOADW(wB, t + 1);
        LOADX(xiB, xjB, t + 1);
        mac_chunk(xiA, xjA, wA, acc);
        if (t + 2 < CHUNKS) {
            LOADW(wA, t + 2);
            LOADX(xiA, xjA, t + 2);
        }
        mac_chunk(xiB, xjB, wB, acc);
    }
#undef LOADW
#undef LOADX

    float lsum = 0.f, accn = 0.f, tpn = 0.f, tnn = 0.f, fpn = 0.f;

    #pragma unroll
    for (int p = 0; p < 2; ++p) {
        #pragma unroll
        for (int q = 0; q < 2; ++q) {
            const int i = i0 + ti + p * 16;
            const int j = j0 + tj + q * 16;
            float l[NC];
            #pragma unroll
            for (int c = 0; c < NC; ++c) l[c] = acc[p][q][c] + bias[c];
            // first-occurrence argmax (matches jnp.argmax)
            int am = 0; float mx = l[0];
            #pragma unroll
            for (int c = 1; c < NC; ++c) { if (l[c] > mx) { mx = l[c]; am = c; } }
            float e[NC];
            float s = 0.f;
            #pragma unroll
            for (int c = 0; c < NC; ++c) { e[c] = __expf(l[c] - mx); s += e[c]; }
            const int spv = sp[p][q];
            // gather l[spv], e[spv] without runtime array index (avoid scratch)
            float lsp = l[0], esp = e[0];
            #pragma unroll
            for (int c = 1; c < NC; ++c) {
                lsp = (spv == c) ? l[c] : lsp;
                esp = (spv == c) ? e[c] : esp;
            }
            const float inv  = __builtin_amdgcn_rcpf(s);
            const float lp   = (lsp - mx) - __logf(s);  // log(prob)
            const float prob = esp * inv;
            const float om   = 1.f - prob;
            const float lm   = -(om * om) * lp;         // focal loss term
            const bool v = (i < sl) && (j < sl);
            const int pred = v ? am : 0;
            out[offs[p][q]] = (float)pred;
            if (v) { lsum += lm; if (pred == spv) accn += 1.f; }
            if (spv > 0) { if (pred == spv) tpn += 1.f; else tnn += 1.f; }
            else if (pred > 0 && v) fpn += 1.f;
        }
    }

    // block reduction: 5 partials -> per-block slot (no atomics, no memset needed)
    float vals[5] = { lsum, accn, tpn, tnn, fpn };
    #pragma unroll
    for (int k = 0; k < 5; ++k) {
        float vv = vals[k];
        for (int o = 32; o > 0; o >>= 1) vv += __shfl_down(vv, o);
        vals[k] = vv;
    }
    const int wave = tid >> 6;
    const int lane = tid & 63;
    if (lane == 0) {
        #pragma unroll
        for (int k = 0; k < 5; ++k) sRed[wave * 5 + k] = vals[k];
    }
    __syncthreads();
    if (tid < 5) {
        float t = sRed[tid] + sRed[5 + tid] + sRed[10 + tid] + sRed[15 + tid];
        accum[(size_t)blk * 5 + tid] = t;
    }
}

__global__ __launch_bounds__(256) void w2ner_final(
    const int* __restrict__ seqlen, const float* __restrict__ accum,
    float* __restrict__ out)
{
    __shared__ float sP[4][5];
    const int tid = threadIdx.x;
    const int nblk = NB * (NN / TILE) * (NN / TILE);   // 1024
    float part[5] = {0.f, 0.f, 0.f, 0.f, 0.f};
    for (int r = tid; r < nblk; r += 256) {
        #pragma unroll
        for (int k = 0; k < 5; ++k) part[k] += accum[(size_t)r * 5 + k];
    }
    #pragma unroll
    for (int k = 0; k < 5; ++k) {
        float v = part[k];
        for (int o = 32; o > 0; o >>= 1) v += __shfl_down(v, o);
        part[k] = v;
    }
    const int wave = tid >> 6;
    const int lane = tid & 63;
    if (lane == 0) {
        #pragma unroll
        for (int k = 0; k < 5; ++k) sP[wave][k] = part[k];
    }
    __syncthreads();
    if (tid == 0) {
        float t[5];
        #pragma unroll
        for (int k = 0; k < 5; ++k) t[k] = sP[0][k] + sP[1][k] + sP[2][k] + sP[3][k];
        float s2 = 0.f;
        for (int k = 0; k < NB; ++k) { float s = (float)seqlen[k]; s2 += s * s; }
        const size_t base = (size_t)NB * NN * NN;
        out[base + 0] = t[2];          // tp
        out[base + 1] = t[3];          // tn
        out[base + 2] = t[4];          // fp
        out[base + 3] = t[0] / s2;     // loss
        out[base + 4] = t[1] / s2;     // accuracy
    }
}

extern "C" void kernel_launch(void* const* d_in, const int* in_sizes, int n_in,
                              void* d_out, int out_size, void* d_ws, size_t ws_size,
                              hipStream_t stream) {
    const float* x      = (const float*)d_in[0];
    const int*   span   = (const int*)d_in[1];
    const int*   seqlen = (const int*)d_in[2];
    const float* Wm     = (const float*)d_in[3];
    const float* bias   = (const float*)d_in[4];
    float* out   = (float*)d_out;
    float* accum = (float*)d_ws;

    const int ntiles = NN / TILE;                      // 16
    dim3 grid(NB * ntiles * ntiles);                   // 1024 blocks
    w2ner_main<<<grid, 256, 0, stream>>>(x, span, seqlen, Wm, bias, out, accum);
    w2ner_final<<<1, 256, 0, stream>>>(seqlen, accum, out);
}

// Round 6
// 49.485 us; speedup vs baseline: 1.1013x; 1.1013x over previous
//
#include <hip/hip_runtime.h>
#include <math.h>

#define NB 4
#define NN 512
#define ND 128
#define NC 10
#define TILE 32
#define CHUNKS (ND/4)  // 32

// one 4-wide d-chunk of the bilinear accumulation (all indices compile-time after inline)
static __device__ __forceinline__ void mac_chunk(
    const float4 (&af)[2], const float4 (&bf)[2], const float (&w)[40],
    float (&acc)[2][2][NC])
{
    float prd[2][2][4];
    #pragma unroll
    for (int p = 0; p < 2; ++p)
        #pragma unroll
        for (int q = 0; q < 2; ++q) {
            prd[p][q][0] = af[p].x * bf[q].x;
            prd[p][q][1] = af[p].y * bf[q].y;
            prd[p][q][2] = af[p].z * bf[q].z;
            prd[p][q][3] = af[p].w * bf[q].w;
        }
    #pragma unroll
    for (int dd = 0; dd < 4; ++dd)
        #pragma unroll
        for (int c = 0; c < NC; ++c)
            #pragma unroll
            for (int p = 0; p < 2; ++p)
                #pragma unroll
                for (int q = 0; q < 2; ++q)
                    acc[p][q][c] = fmaf(prd[p][q][dd], w[dd * NC + c], acc[p][q][c]);
}

__global__ __launch_bounds__(256) void w2ner_main(
    const float* __restrict__ x, const int* __restrict__ span,
    const int* __restrict__ seqlen, const float* __restrict__ Wm,
    const float* __restrict__ bias, float* __restrict__ out,
    float* __restrict__ accum)
{
    __shared__ float sRed[4 * 5];

    const int tid = threadIdx.x;
    const int ntj = NN / TILE;                  // 16
    const int blk = blockIdx.x;
    const int b   = blk / (ntj * ntj);
    const int rem = blk % (ntj * ntj);
    const int i0  = (rem / ntj) * TILE;
    const int j0  = (rem % ntj) * TILE;

    const float* xb = x + (size_t)b * NN * ND;

    const int ti = tid >> 4;   // 0..15 -> rows ti, ti+16
    const int tj = tid & 15;   // 0..15 -> cols tj, tj+16

    // prefetch span for the 4 pairs this thread owns (hides under K-loop)
    size_t offs[2][2];
    int sp[2][2];
    #pragma unroll
    for (int p = 0; p < 2; ++p)
        #pragma unroll
        for (int q = 0; q < 2; ++q) {
            const int i = i0 + ti + p * 16;
            const int j = j0 + tj + q * 16;
            offs[p][q] = (size_t)b * NN * NN + (size_t)i * NN + j;
            sp[p][q]   = span[offs[p][q]];
        }
    const int sl = seqlen[b];

    float acc[2][2][NC];
    #pragma unroll
    for (int p = 0; p < 2; ++p)
        #pragma unroll
        for (int q = 0; q < 2; ++q)
            #pragma unroll
            for (int c = 0; c < NC; ++c) acc[p][q][c] = 0.f;

    // All X reads per-lane from global (vmcnt queue, counted in-order waits,
    // L1/L2-hot 16 KB tiles). W reads wave-uniform from global (scalar s_load,
    // lgkm queue, contiguous 160 B per chunk). Queues stay separate -> the
    // compiler can pipeline both without lgkmcnt(0) killing VMEM prefetch.
    const float* gXi0 = xb + (size_t)(i0 + ti) * ND;
    const float* gXi1 = xb + (size_t)(i0 + ti + 16) * ND;
    const float* gXj0 = xb + (size_t)(j0 + tj) * ND;
    const float* gXj1 = xb + (size_t)(j0 + tj + 16) * ND;

    #pragma unroll 4
    for (int t = 0; t < CHUNKS; ++t) {
        float4 af[2], bf[2];
        af[0] = *reinterpret_cast<const float4*>(gXi0 + 4 * t);
        af[1] = *reinterpret_cast<const float4*>(gXi1 + 4 * t);
        bf[0] = *reinterpret_cast<const float4*>(gXj0 + 4 * t);
        bf[1] = *reinterpret_cast<const float4*>(gXj1 + 4 * t);
        float w[40];
        const float* wp = Wm + 40 * t;   // contiguous 40 dwords, wave-uniform
        #pragma unroll
        for (int k = 0; k < 40; ++k) w[k] = wp[k];
        mac_chunk(af, bf, w, acc);
    }

    float lsum = 0.f, accn = 0.f, tpn = 0.f, tnn = 0.f, fpn = 0.f;

    #pragma unroll
    for (int p = 0; p < 2; ++p) {
        #pragma unroll
        for (int q = 0; q < 2; ++q) {
            const int i = i0 + ti + p * 16;
            const int j = j0 + tj + q * 16;
            float l[NC];
            #pragma unroll
            for (int c = 0; c < NC; ++c) l[c] = acc[p][q][c] + bias[c];
            // first-occurrence argmax (matches jnp.argmax)
            int am = 0; float mx = l[0];
            #pragma unroll
            for (int c = 1; c < NC; ++c) { if (l[c] > mx) { mx = l[c]; am = c; } }
            float e[NC];
            float s = 0.f;
            #pragma unroll
            for (int c = 0; c < NC; ++c) { e[c] = __expf(l[c] - mx); s += e[c]; }
            const int spv = sp[p][q];
            // gather l[spv], e[spv] without runtime array index (avoid scratch)
            float lsp = l[0], esp = e[0];
            #pragma unroll
            for (int c = 1; c < NC; ++c) {
                lsp = (spv == c) ? l[c] : lsp;
                esp = (spv == c) ? e[c] : esp;
            }
            const float inv  = __builtin_amdgcn_rcpf(s);
            const float lp   = (lsp - mx) - __logf(s);  // log(prob)
            const float prob = esp * inv;
            const float om   = 1.f - prob;
            const float lm   = -(om * om) * lp;         // focal loss term
            const bool v = (i < sl) && (j < sl);
            const int pred = v ? am : 0;
            out[offs[p][q]] = (float)pred;
            if (v) { lsum += lm; if (pred == spv) accn += 1.f; }
            if (spv > 0) { if (pred == spv) tpn += 1.f; else tnn += 1.f; }
            else if (pred > 0 && v) fpn += 1.f;
        }
    }

    // block reduction: 5 partials -> per-block slot (no atomics, no memset needed)
    float vals[5] = { lsum, accn, tpn, tnn, fpn };
    #pragma unroll
    for (int k = 0; k < 5; ++k) {
        float vv = vals[k];
        for (int o = 32; o > 0; o >>= 1) vv += __shfl_down(vv, o);
        vals[k] = vv;
    }
    const int wave = tid >> 6;
    const int lane = tid & 63;
    if (lane == 0) {
        #pragma unroll
        for (int k = 0; k < 5; ++k) sRed[wave * 5 + k] = vals[k];
    }
    __syncthreads();
    if (tid < 5) {
        float t = sRed[tid] + sRed[5 + tid] + sRed[10 + tid] + sRed[15 + tid];
        accum[(size_t)blk * 5 + tid] = t;
    }
}

__global__ __launch_bounds__(256) void w2ner_final(
    const int* __restrict__ seqlen, const float* __restrict__ accum,
    float* __restrict__ out)
{
    __shared__ float sP[4][5];
    const int tid = threadIdx.x;
    const int nblk = NB * (NN / TILE) * (NN / TILE);   // 1024
    float part[5] = {0.f, 0.f, 0.f, 0.f, 0.f};
    for (int r = tid; r < nblk; r += 256) {
        #pragma unroll
        for (int k = 0; k < 5; ++k) part[k] += accum[(size_t)r * 5 + k];
    }
    #pragma unroll
    for (int k = 0; k < 5; ++k) {
        float v = part[k];
        for (int o = 32; o > 0; o >>= 1) v += __shfl_down(v, o);
        part[k] = v;
    }
    const int wave = tid >> 6;
    const int lane = tid & 63;
    if (lane == 0) {
        #pragma unroll
        for (int k = 0; k < 5; ++k) sP[wave][k] = part[k];
    }
    __syncthreads();
    if (tid == 0) {
        float t[5];
        #pragma unroll
        for (int k = 0; k < 5; ++k) t[k] = sP[0][k] + sP[1][k] + sP[2][k] + sP[3][k];
        float s2 = 0.f;
        for (int k = 0; k < NB; ++k) { float s = (float)seqlen[k]; s2 += s * s; }
        const size_t base = (size_t)NB * NN * NN;
        out[base + 0] = t[2];          // tp
        out[base + 1] = t[3];          // tn
        out[base + 2] = t[4];          // fp
        out[base + 3] = t[0] / s2;     // loss
        out[base + 4] = t[1] / s2;     // accuracy
    }
}

extern "C" void kernel_launch(void* const* d_in, const int* in_sizes, int n_in,
                              void* d_out, int out_size, void* d_ws, size_t ws_size,
                              hipStream_t stream) {
    const float* x      = (const float*)d_in[0];
    const int*   span   = (const int*)d_in[1];
    const int*   seqlen = (const int*)d_in[2];
    const float* Wm     = (const float*)d_in[3];
    const float* bias   = (const float*)d_in[4];
    float* out   = (float*)d_out;
    float* accum = (float*)d_ws;

    const int ntiles = NN / TILE;                      // 16
    dim3 grid(NB * ntiles * ntiles);                   // 1024 blocks
    w2ner_main<<<grid, 256, 0, stream>>>(x, span, seqlen, Wm, bias, out, accum);
    w2ner_final<<<1, 256, 0, stream>>>(seqlen, accum, out);
}

// Round 7
// 32.591 us; speedup vs baseline: 1.6722x; 1.5183x over previous
//
#include <hip/hip_runtime.h>
#include <math.h>

#define NB 4
#define NN 512
#define ND 128
#define NC 10
#define TI 16          // square tile edge
#define NTILE (NN/TI)  // 32
#define TPB (NTILE*(NTILE+1)/2)   // 528 tile-pairs per batch (upper triangle incl diag)
#define PAD 132
#define CHUNKS (ND/4)  // 32

typedef float f32x2 __attribute__((ext_vector_type(2)));

// one direction's span-dependent epilogue (focal loss + counters)
static __device__ __forceinline__ void dir_epilogue(
    const float (&l)[NC], const float (&e)[NC], float mx, float lgs, float inv,
    int pred, bool v, int sp,
    float& lsum, float& accn, float& tpn, float& tnn, float& fpn)
{
    float lsp = l[0], esp = e[0];
    #pragma unroll
    for (int c = 1; c < NC; ++c) {
        lsp = (sp == c) ? l[c] : lsp;
        esp = (sp == c) ? e[c] : esp;
    }
    const float lp   = (lsp - mx) - lgs;   // log(prob)
    const float prob = esp * inv;
    const float om   = 1.f - prob;
    const float lm   = -(om * om) * lp;    // focal loss term
    if (v) { lsum += lm; if (pred == sp) accn += 1.f; }
    if (sp > 0) { if (pred == sp) tpn += 1.f; else tnn += 1.f; }
    else if (pred > 0 && v) fpn += 1.f;
}

__global__ __launch_bounds__(256) void w2ner_main(
    const float* __restrict__ x, const int* __restrict__ span,
    const int* __restrict__ seqlen, const float* __restrict__ Wm,
    const float* __restrict__ bias, float* __restrict__ out,
    float* __restrict__ accum, int use_slots)
{
    __shared__ float sXj[TI * PAD];
    __shared__ float sRed[4 * 5];

    const int tid = threadIdx.x;
    const int blk = blockIdx.x;
    const int b   = blk / TPB;
    int m = blk % TPB;

    // map m -> (Ti, Tj) with Tj >= Ti (upper-triangle tile pairs)
    int Ti = 0;
    while (m >= (NTILE - Ti)) { m -= (NTILE - Ti); ++Ti; }
    const int Tj = Ti + m;
    const bool mirror = (Tj > Ti);

    const int i0 = Ti * TI, j0 = Tj * TI;
    const float* xb = x + (size_t)b * NN * ND;

    // stage Xj tile (16 rows, coalesced float4)
    for (int idx = tid; idx < TI * (ND / 4); idx += 256) {
        int row = idx >> 5, c4 = (idx & 31) << 2;
        float4 v = *reinterpret_cast<const float4*>(xb + (size_t)(j0 + row) * ND + c4);
        *reinterpret_cast<float4*>(sXj + row * PAD + c4) = v;
    }

    const int r  = tid >> 4;   // i-row within tile
    const int cc = tid & 15;   // j-col within tile
    const int i = i0 + r, j = j0 + cc;

    // prefetch span (both directions) before the K-loop; latency hides under FMA
    const size_t offA = (size_t)b * NN * NN + (size_t)i * NN + j;
    const int spA = span[offA];
    size_t offB = 0; int spB = 0;
    if (mirror) { offB = (size_t)b * NN * NN + (size_t)j * NN + i; spB = span[offB]; }
    const int sl = seqlen[b];

    __syncthreads();

    f32x2 acc2[5];
    #pragma unroll
    for (int k = 0; k < 5; ++k) acc2[k] = (f32x2){0.f, 0.f};

    // Xi per-lane from global: 16 lanes share each address -> broadcast (L1/L2 hot)
    // Xj from LDS. W wave-uniform f32x2 -> scalar s_load path.
    const float* gXi = xb + (size_t)i * ND;
    const float* pXj = sXj + cc * PAD;

    #pragma unroll 4
    for (int t = 0; t < CHUNKS; ++t) {
        float4 a  = *reinterpret_cast<const float4*>(gXi + 4 * t);
        float4 bq = *reinterpret_cast<const float4*>(pXj + 4 * t);
        float pr[4] = { a.x * bq.x, a.y * bq.y, a.z * bq.z, a.w * bq.w };
        #pragma unroll
        for (int dd = 0; dd < 4; ++dd) {
            const f32x2* Wrow = reinterpret_cast<const f32x2*>(Wm + (size_t)(4 * t + dd) * NC);
            const f32x2 pv = (f32x2){ pr[dd], pr[dd] };
            #pragma unroll
            for (int k = 0; k < 5; ++k)
                acc2[k] = __builtin_elementwise_fma(pv, Wrow[k], acc2[k]);
        }
    }

    // shared (symmetric) part of the epilogue
    float l[NC];
    #pragma unroll
    for (int k = 0; k < 5; ++k) {
        l[2 * k]     = acc2[k].x + bias[2 * k];
        l[2 * k + 1] = acc2[k].y + bias[2 * k + 1];
    }
    int am = 0; float mx = l[0];
    #pragma unroll
    for (int c = 1; c < NC; ++c) { if (l[c] > mx) { mx = l[c]; am = c; } }   // first-occurrence argmax
    float e[NC]; float s = 0.f;
    #pragma unroll
    for (int c = 0; c < NC; ++c) { e[c] = __expf(l[c] - mx); s += e[c]; }
    const float inv = __builtin_amdgcn_rcpf(s);
    const float lgs = __logf(s);
    const bool v = (i < sl) && (j < sl);
    const int pred = v ? am : 0;

    float lsum = 0.f, accn = 0.f, tpn = 0.f, tnn = 0.f, fpn = 0.f;
    out[offA] = (float)pred;
    dir_epilogue(l, e, mx, lgs, inv, pred, v, spA, lsum, accn, tpn, tnn, fpn);
    if (mirror) {
        out[offB] = (float)pred;   // predict is symmetric
        dir_epilogue(l, e, mx, lgs, inv, pred, v, spB, lsum, accn, tpn, tnn, fpn);
    }

    // block reduction: 5 partials
    float vals[5] = { lsum, accn, tpn, tnn, fpn };
    #pragma unroll
    for (int k = 0; k < 5; ++k) {
        float vv = vals[k];
        for (int o = 32; o > 0; o >>= 1) vv += __shfl_down(vv, o);
        vals[k] = vv;
    }
    const int wave = tid >> 6;
    const int lane = tid & 63;
    if (lane == 0) {
        #pragma unroll
        for (int k = 0; k < 5; ++k) sRed[wave * 5 + k] = vals[k];
    }
    __syncthreads();
    if (tid < 5) {
        float t = sRed[tid] + sRed[5 + tid] + sRed[10 + tid] + sRed[15 + tid];
        if (use_slots) accum[(size_t)blk * 5 + tid] = t;
        else atomicAdd(&accum[tid], t);
    }
}

__global__ __launch_bounds__(256) void w2ner_final(
    const int* __restrict__ seqlen, const float* __restrict__ accum,
    float* __restrict__ out, int use_slots)
{
    __shared__ float sP[4][5];
    const int tid = threadIdx.x;
    const int nblk = NB * TPB;   // 2112
    float part[5] = {0.f, 0.f, 0.f, 0.f, 0.f};
    if (use_slots) {
        for (int r = tid; r < nblk; r += 256) {
            #pragma unroll
            for (int k = 0; k < 5; ++k) part[k] += accum[(size_t)r * 5 + k];
        }
    } else if (tid < 5) {
        part[0] = 0.f;  // handled below via direct read
    }
    #pragma unroll
    for (int k = 0; k < 5; ++k) {
        float v = part[k];
        for (int o = 32; o > 0; o >>= 1) v += __shfl_down(v, o);
        part[k] = v;
    }
    const int wave = tid >> 6;
    const int lane = tid & 63;
    if (lane == 0) {
        #pragma unroll
        for (int k = 0; k < 5; ++k) sP[wave][k] = part[k];
    }
    __syncthreads();
    if (tid == 0) {
        float t[5];
        #pragma unroll
        for (int k = 0; k < 5; ++k)
            t[k] = use_slots ? (sP[0][k] + sP[1][k] + sP[2][k] + sP[3][k]) : accum[k];
        float s2 = 0.f;
        for (int k = 0; k < NB; ++k) { float s = (float)seqlen[k]; s2 += s * s; }
        const size_t base = (size_t)NB * NN * NN;
        out[base + 0] = t[2];          // tp
        out[base + 1] = t[3];          // tn
        out[base + 2] = t[4];          // fp
        out[base + 3] = t[0] / s2;     // loss
        out[base + 4] = t[1] / s2;     // accuracy
    }
}

extern "C" void kernel_launch(void* const* d_in, const int* in_sizes, int n_in,
                              void* d_out, int out_size, void* d_ws, size_t ws_size,
                              hipStream_t stream) {
    const float* x      = (const float*)d_in[0];
    const int*   span   = (const int*)d_in[1];
    const int*   seqlen = (const int*)d_in[2];
    const float* Wm     = (const float*)d_in[3];
    const float* bias   = (const float*)d_in[4];
    float* out   = (float*)d_out;
    float* accum = (float*)d_ws;

    const int nblk = NB * TPB;                         // 2112 blocks
    const size_t need = (size_t)nblk * 5 * sizeof(float);
    const int use_slots = (ws_size >= need) ? 1 : 0;
    if (!use_slots) hipMemsetAsync(accum, 0, 5 * sizeof(float), stream);

    w2ner_main<<<dim3(nblk), 256, 0, stream>>>(x, span, seqlen, Wm, bias, out, accum, use_slots);
    w2ner_final<<<1, 256, 0, stream>>>(seqlen, accum, out, use_slots);
}